// Round 2
// baseline (151.369 us; speedup 1.0000x reference)
//
#include <hip/hip_runtime.h>

// Problem constants (fixed by the reference)
#define NN   16
#define DD   3
#define HH   160
#define WW   160
#define MM   8
#define KK   10
#define PP   15
#define PM   7            // (P-1)/2
#define OUTH 146          // H - P + 1
#define OUTW 146
#define MK   (MM*KK)      // 80
#define YT   73           // row-pairs per plane (146/2)
#define XT   37           // col-quads per plane (ceil(146/4), last overlaps)
#define UNITS (YT*XT)     // 2701 micro-tiles per (mk,n) plane

typedef float vfloat2 __attribute__((ext_vector_type(2)));

__global__ __launch_bounds__(256)
void fern_bits_kernel(const float* __restrict__ T,
                      const float* __restrict__ dx1,
                      const float* __restrict__ dx2,
                      const float* __restrict__ dy1,
                      const float* __restrict__ dy2,
                      const float* __restrict__ th,
                      const float* __restrict__ amb,
                      const int*   __restrict__ channels,
                      float* __restrict__ out)
{
    const int mk = blockIdx.y;       // 0..79
    const int n  = blockIdx.z;       // 0..15
    const int k  = mk % KK;
    const int m  = mk / KK;
    const int c  = channels[k];

    // Per-feature (block-uniform) parameters — compile to scalar loads
    float a, f;
    a = dx1[mk]; f = floorf(a); const float fx1 = a - f; const int sx1 = PM + (int)f;
    a = dy1[mk]; f = floorf(a); const float fy1 = a - f; const int sy1 = PM + (int)f;
    a = dx2[mk]; f = floorf(a); const float fx2 = a - f; const int sx2 = PM + (int)f;
    a = dy2[mk]; f = floorf(a); const float fy2 = a - f; const int sy2 = PM + (int)f;
    const float thv = th[mk];
    const float pos = amb[(m*2 + 0)*KK + k];
    const float neg = amb[(m*2 + 1)*KK + k];
    const float scl = 1.0f / (pos - neg + 1e-29f);

    const float* __restrict__ Tp = T + (size_t)(n*DD + c) * (HH*WW);

    const int u = blockIdx.x * 256 + threadIdx.x;
    if (u >= UNITS) return;
    const int ty = u / XT;               // 0..72  (row-pair index)
    const int tx = u - ty * XT;          // 0..36  (col-quad index)
    const int y  = ty * 2;
    int x = tx * 4;
    if (x > OUTW - 4) x = OUTW - 4;      // tail: overlap-recompute cols 142..145 (bit-identical dup stores)

    // Sample bases; sample-2 offset from sample-1 is block-uniform
    const float* r1 = Tp + (sy1 + y) * WW + (sx1 + x);
    const float* r2 = Tp + (sy2 + y) * WW + (sx2 + x);

    // Issue all 30 loads up front (immediate offsets, 2 base addrs) for max MLP
    float v1v[3][5], v2v[3][5];
#pragma unroll
    for (int j = 0; j < 3; ++j) {
#pragma unroll
        for (int i = 0; i < 5; ++i) {
            v1v[j][i] = r1[j * WW + i];
            v2v[j][i] = r2[j * WW + i];
        }
    }

    // Horizontal lerps: one per input row, shared by both output rows
    float h1[3][4], h2[3][4];
#pragma unroll
    for (int j = 0; j < 3; ++j) {
#pragma unroll
        for (int i = 0; i < 4; ++i) {
            h1[j][i] = v1v[j][i] + fx1 * (v1v[j][i+1] - v1v[j][i]);
            h2[j][i] = v2v[j][i] + fx2 * (v2v[j][i+1] - v2v[j][i]);
        }
    }

    // Vertical lerps: row j is bottom of output-row 0 and top of output-row 1
    float q1a[4], q1b[4], q2a[4], q2b[4];
#pragma unroll
    for (int i = 0; i < 4; ++i) {
        q1a[i] = h1[0][i] + fy1 * (h1[1][i] - h1[0][i]);
        q1b[i] = h1[1][i] + fy1 * (h1[2][i] - h1[1][i]);
        q2a[i] = h2[0][i] + fy2 * (h2[1][i] - h2[0][i]);
        q2b[i] = h2[1][i] + fy2 * (h2[2][i] - h2[1][i]);
    }

    // Epilogue: deadzone, threshold, clamp (fmed3 = 1-instr clamp)
    float o0[4], o1[4];
#pragma unroll
    for (int i = 0; i < 4; ++i) {
        float d0 = q1a[i] - q2a[i]; if (fabsf(d0) < 1e-5f) d0 = 0.0f;
        float d1 = q1b[i] - q2b[i]; if (fabsf(d1) < 1e-5f) d1 = 0.0f;
        o0[i] = __builtin_amdgcn_fmed3f((d0 - thv - neg) * scl, 0.0f, 1.0f);
        o1[i] = __builtin_amdgcn_fmed3f((d1 - thv - neg) * scl, 0.0f, 1.0f);
    }

    // Stores: 4x float2 (8B-aligned: x even, OUTW even), nontemporal (109MB stream >> L2)
    float* orow0 = out + ((size_t)(n * MK + mk) * OUTH + y) * OUTW + x;
    float* orow1 = orow0 + OUTW;
    vfloat2 s;
    s.x = o0[0]; s.y = o0[1]; __builtin_nontemporal_store(s, (vfloat2*)(orow0));
    s.x = o0[2]; s.y = o0[3]; __builtin_nontemporal_store(s, (vfloat2*)(orow0 + 2));
    s.x = o1[0]; s.y = o1[1]; __builtin_nontemporal_store(s, (vfloat2*)(orow1));
    s.x = o1[2]; s.y = o1[3]; __builtin_nontemporal_store(s, (vfloat2*)(orow1 + 2));
}

extern "C" void kernel_launch(void* const* d_in, const int* in_sizes, int n_in,
                              void* d_out, int out_size, void* d_ws, size_t ws_size,
                              hipStream_t stream) {
    const float* T        = (const float*)d_in[0];
    const float* dx1      = (const float*)d_in[1];
    const float* dx2      = (const float*)d_in[2];
    const float* dy1      = (const float*)d_in[3];
    const float* dy2      = (const float*)d_in[4];
    const float* th       = (const float*)d_in[5];
    const float* amb      = (const float*)d_in[6];
    const int*   channels = (const int*)d_in[7];
    // d_in[8] = patch_size scalar (compile-time constant PP=15 here)
    float* out = (float*)d_out;

    dim3 grid((UNITS + 255) / 256, MK, NN);
    dim3 block(256, 1, 1);
    fern_bits_kernel<<<grid, block, 0, stream>>>(T, dx1, dx2, dy1, dy2, th, amb,
                                                 channels, out);
}